// Round 13
// baseline (58.750 us; speedup 1.0000x reference)
//
#include <hip/hip_runtime.h>

typedef short bf16x8 __attribute__((ext_vector_type(8)));
typedef unsigned short u16;
typedef u16 u16x4 __attribute__((ext_vector_type(4)));
typedef float f32x4 __attribute__((ext_vector_type(4)));

constexpr int TPB  = 512;   // 8 waves (fused kernel)
constexpr int FTPB = 256;   // finalize kernel block size (fixed!)
constexpr int RPB  = 64;    // rows per block
constexpr int DIM  = 300;   // embedding dim
constexpr int KPAD = 320;   // padded K (10 x 32)
constexpr int NKT  = 10;    // K-steps of 32
constexpr int H1N  = 64;
constexpr int H2N  = 32;
constexpr int NA   = 18;
constexpr int NK   = 32;
constexpr int NC   = 384;
constexpr float LOG_HALF = -0.6931471805599453f;

__device__ __forceinline__ float fast_sigmoid(float z) {
    return __builtin_amdgcn_rcpf(1.0f + __expf(-z));
}
__device__ __forceinline__ float lsig(float z) {           // stable log(sigmoid(z))
    return fminf(z, 0.0f) - __logf(1.0f + __expf(-fabsf(z)));
}
__device__ __forceinline__ u16 f2bf(float f) {             // f32 -> bf16 RNE
    unsigned u = __builtin_bit_cast(unsigned, f);
    return (u16)((u + 0x7FFFu + ((u >> 16) & 1u)) >> 16);
}
// spread 8 bits to 8 nibbles (bit a -> bit 4a)
__device__ __forceinline__ unsigned spread8(unsigned v) {
    v = (v | (v << 12)) & 0x000F000Fu;
    v = (v | (v << 6))  & 0x03030303u;
    v = (v | (v << 3))  & 0x11111111u;
    return v;
}

// prep: W1->bf16 W1T[64][320], W2->bf16 W2T[32][64], W3->bf16 W3T[32][32] (cols>=18 zero),
//       codebook -> 18-bit masks
__global__ __launch_bounds__(384)
void prep_k(const float* __restrict__ W1, const float* __restrict__ W2,
            const float* __restrict__ W3, const float* __restrict__ cbf,
            u16* __restrict__ w1t, u16* __restrict__ w2t, u16* __restrict__ w3t,
            unsigned* __restrict__ cbw)
{
    const int c = blockIdx.x;
    const int t = threadIdx.x;
    if (c < 64) {
        if (t < KPAD)
            w1t[c * KPAD + t] = f2bf((t < DIM) ? W1[t * H1N + c] : 0.0f);
    } else if (c == 64) {
        if (t < NC) {
            unsigned bits = 0u;
            #pragma unroll
            for (int a = 0; a < NA; ++a)
                bits |= (cbf[t * NA + a] != 0.0f) ? (1u << a) : 0u;
            cbw[t] = bits;
        }
    } else if (c == 65) {
        for (int e = t; e < H2N * H1N; e += 384) {       // w2t[n][k] = W2[k][n]
            const int n = e >> 6, k = e & 63;
            w2t[e] = f2bf(W2[k * H2N + n]);
        }
    } else {
        for (int e = t; e < H2N * H2N; e += 384) {       // w3t[n][k] = W3[k][n], n>=18 -> 0
            const int n = e >> 5, k = e & 31;
            w3t[e] = f2bf((n < NA) ? W3[k * NA + n] : 0.0f);
        }
    }
}

__global__ __launch_bounds__(TPB, 6)
void fused_mf2(const float* __restrict__ x, const float* __restrict__ y,
               const float* __restrict__ ob, const float* __restrict__ b1,
               const float* __restrict__ b2, const float* __restrict__ b3,
               const int* __restrict__ neg_idx,
               const u16* __restrict__ w1t, const u16* __restrict__ w2t,
               const u16* __restrict__ w3t, const unsigned* __restrict__ cbw,
               float* __restrict__ out_wu, float2* __restrict__ blk_part)
{
    __shared__ __align__(16) unsigned char smem[40960];
    u16*      xs      = (u16*)smem;                 // [64][320] bf16, phase 1 only
    u16*      h1s     = (u16*)smem;                 // [64][64]  bf16, bytes 0..8191
    u16*      h2s     = (u16*)(smem + 8192);        // [64][32]  bf16, 4 KiB
    float*    wus     = (float*)(smem + 12288);     // [64][20]  f32,  5120 B
    unsigned* cb_bits = (unsigned*)(smem + 17408);  // 1536 B
    float*    wsum    = (float*)(smem + 18944);
    int*      wcnt    = (int*)(smem + 18960);

    const int tid  = threadIdx.x;
    const int lane = tid & 63;
    const int wv   = tid >> 6;            // 0..7
    const int l15  = lane & 15;
    const int kg   = (lane >> 4) * 8;     // k-group within a K=32 step
    const int rh   = wv >> 2;             // phase-1 row half
    const int cq   = wv & 3;              // phase-1 col quarter
    const long brow = (long)blockIdx.x * RPB;
    const float* xg = x + brow * DIM;

    // ---- stage x: pipelined sub-batches, <=7 float4 live (no scratch spill) ----
    // order pinned: LA(4), LB(3), WA, LC(3), WB, WC   (10 chunks of 512 float4)
    float4 va[4], vb[3], vc[3];
    #pragma unroll
    for (int ch = 0; ch < 4; ++ch)
        va[ch] = *(const float4*)(xg + (long)(ch * TPB + tid) * 4);
    #pragma unroll
    for (int ch = 0; ch < 3; ++ch)
        vb[ch] = *(const float4*)(xg + (long)((4 + ch) * TPB + tid) * 4);
    __builtin_amdgcn_sched_barrier(0);
    #pragma unroll
    for (int ch = 0; ch < 4; ++ch) {                        // WA
        const int f = ch * TPB + tid;
        const int row = f / 75, k = (f - row * 75) * 4;
        const int kk = k ^ ((row & 7) << 3);                // in-row XOR swizzle
        u16x4 pk = { f2bf(va[ch].x), f2bf(va[ch].y), f2bf(va[ch].z), f2bf(va[ch].w) };
        *(u16x4*)(xs + row * KPAD + kk) = pk;
    }
    __builtin_amdgcn_sched_barrier(0);
    #pragma unroll
    for (int ch = 0; ch < 3; ++ch) {                        // LC (last chunk partial)
        const int f = (7 + ch) * TPB + tid;
        vc[ch] = (ch < 2 || f < 4800) ? *(const float4*)(xg + (long)f * 4)
                                      : make_float4(0.f, 0.f, 0.f, 0.f);
    }
    __builtin_amdgcn_sched_barrier(0);
    #pragma unroll
    for (int ch = 0; ch < 3; ++ch) {                        // WB
        const int f = (4 + ch) * TPB + tid;
        const int row = f / 75, k = (f - row * 75) * 4;
        const int kk = k ^ ((row & 7) << 3);
        u16x4 pk = { f2bf(vb[ch].x), f2bf(vb[ch].y), f2bf(vb[ch].z), f2bf(vb[ch].w) };
        *(u16x4*)(xs + row * KPAD + kk) = pk;
    }
    #pragma unroll
    for (int ch = 0; ch < 3; ++ch) {                        // WC
        const int f = (7 + ch) * TPB + tid;
        if (ch < 2 || f < 4800) {
            const int row = f / 75, k = (f - row * 75) * 4;
            const int kk = k ^ ((row & 7) << 3);
            u16x4 pk = { f2bf(vc[ch].x), f2bf(vc[ch].y), f2bf(vc[ch].z), f2bf(vc[ch].w) };
            *(u16x4*)(xs + row * KPAD + kk) = pk;
        }
    }
    #pragma unroll
    for (int uu = 0; uu < 3; ++uu) {                        // zero-pad k in [300,320)
        const int e = uu * TPB + tid;                       // 1280 total
        if (uu < 2 || tid < 256) {
            const int row = e / 20, kp = e - row * 20;
            xs[row * KPAD + ((DIM + kp) ^ ((row & 7) << 3))] = 0;
        }
    }

    // ---- W1 B-frags (L2-hot) + codebook reg; b1 drains vmcnt anyway ----
    const int colB = cq * 16 + l15;
    bf16x8 bfr[NKT];                                        // 40 VGPR
    #pragma unroll
    for (int kt = 0; kt < NKT; ++kt)
        bfr[kt] = *(const bf16x8*)(w1t + colB * KPAD + kt * 32 + kg);
    const unsigned cbv0 = (tid < NC) ? cbw[tid] : 0u;

    __syncthreads();                                        // b1: xs ready

    // ---- phase 1: x @ W1 (2 row-tiles x 10 K-steps per wave) ----
    f32x4 acc[2];
    #pragma unroll
    for (int rt = 0; rt < 2; ++rt) acc[rt] = (f32x4){0.f, 0.f, 0.f, 0.f};
    #pragma unroll
    for (int kt = 0; kt < NKT; ++kt) {
        bf16x8 afr[2];
        #pragma unroll
        for (int rt = 0; rt < 2; ++rt) {
            const int row = rh * 32 + rt * 16 + l15;
            afr[rt] = *(const bf16x8*)(xs + ((row * KPAD + kt * 32 + kg) ^ ((row & 7) << 3)));
        }
        #pragma unroll
        for (int rt = 0; rt < 2; ++rt)
            acc[rt] = __builtin_amdgcn_mfma_f32_16x16x32_bf16(afr[rt], bfr[kt], acc[rt], 0, 0, 0);
    }
    __syncthreads();                                        // b2: xs reads done

    // ---- epilogue 1: bias+sigmoid -> h1s (swizzled, aliases xs) ----
    const float b1v = b1[colB];
    #pragma unroll
    for (int rt = 0; rt < 2; ++rt) {
        #pragma unroll
        for (int j = 0; j < 4; ++j) {
            const int row = rh * 32 + rt * 16 + (lane >> 4) * 4 + j;  // C/D map (m89)
            h1s[(row * H1N + colB) ^ ((row & 7) << 3)] = f2bf(fast_sigmoid(acc[rt][j] + b1v));
        }
    }
    if (tid < NC) cb_bits[tid] = cbv0;

    // ---- loss-input loads (waves 0-3 only): fly under epilogue/phases ----
    const int rloc = (wv & 3) * 16 + (lane >> 2);
    const int p    = lane & 3;
    const long bds = brow + rloc;
    int4 n0 = make_int4(0, 0, 0, 0), n1 = make_int4(0, 0, 0, 0);
    float2 oA = make_float2(0.f, 0.f), oB = oA, yA = oA, yB = oA;
    float oT = 0.f, yT = 0.f;
    if (wv < 4) {
        const int4* nbp = (const int4*)(neg_idx + bds * NK + p * 8);
        n0 = nbp[0]; n1 = nbp[1];
        const float* obr = ob + bds * NA + p * 4;
        oA = *(const float2*)obr; oB = *(const float2*)(obr + 2);
        if (p < 2) oT = ob[bds * NA + 16 + p];
        const float* yr = y + bds * NA + p * 4;
        yA = *(const float2*)yr; yB = *(const float2*)(yr + 2);
        if (p < 2) yT = y[bds * NA + 16 + p];
    }

    __syncthreads();                                        // b3: h1s + cb ready

    // ---- phase 2: h1 @ W2 (4 row-groups x 2 col-halves across 8 waves) ----
    const int rowA = (wv & 3) * 16 + l15;
    const int ct2  = wv >> 2;
    const int colC = ct2 * 16 + l15;
    bf16x8 a2[2];
    #pragma unroll
    for (int kt = 0; kt < 2; ++kt)
        a2[kt] = *(const bf16x8*)(h1s + ((rowA * H1N + kt * 32 + kg) ^ ((rowA & 7) << 3)));
    const float bb2 = b2[colC];
    f32x4 acc2 = (f32x4){bb2, bb2, bb2, bb2};
    #pragma unroll
    for (int kt = 0; kt < 2; ++kt) {
        const bf16x8 bfr2 = *(const bf16x8*)(w2t + colC * H1N + kt * 32 + kg);
        acc2 = __builtin_amdgcn_mfma_f32_16x16x32_bf16(a2[kt], bfr2, acc2, 0, 0, 0);
    }
    #pragma unroll
    for (int j = 0; j < 4; ++j) {
        const int row = (wv & 3) * 16 + (lane >> 4) * 4 + j;
        h2s[(row * H2N + colC) ^ ((row & 3) << 3)] = f2bf(fast_sigmoid(acc2[j]));
    }
    __syncthreads();                                        // b3b: h2s complete (cross-wave)

    // ---- phase 3: h2 @ W3 ----
    const bf16x8 a3 = *(const bf16x8*)(h2s + ((rowA * H2N + kg) ^ ((rowA & 3) << 3)));
    const float bb3 = (colC < NA) ? b3[colC] : 0.f;
    f32x4 acc3 = (f32x4){bb3, bb3, bb3, bb3};
    {
        const bf16x8 bfr3 = *(const bf16x8*)(w3t + colC * H2N + kg);
        acc3 = __builtin_amdgcn_mfma_f32_16x16x32_bf16(a3, bfr3, acc3, 0, 0, 0);
    }
    #pragma unroll
    for (int j = 0; j < 4; ++j) {
        const int row = (wv & 3) * 16 + (lane >> 4) * 4 + j;
        if (ct2 == 0)          wus[row * 20 + l15] = acc3[j];
        else if (l15 < 2)      wus[row * 20 + 16 + l15] = acc3[j];
    }
    __syncthreads();                                        // b3c: wus complete (cross-wave)

    // ---- loss: waves 0-3, 4 lanes/row ----
    if (wv < 4) {
        const float4 wA = *(const float4*)(wus + rloc * 20 + p * 4);
        const float  wT = (p < 2) ? wus[rloc * 20 + 16 + p] : 0.f;

        const float wcv[4] = {wA.x * oA.x, wA.y * oA.y, wA.z * oB.x, wA.w * oB.y};
        const float yvv[4] = {yA.x, yA.y, yB.x, yB.y};
        const float wcT = wT * oT;
        float ssum = wcv[0] + wcv[1] + wcv[2] + wcv[3] + wcT;
        ssum += __shfl_xor(ssum, 1);
        ssum += __shfl_xor(ssum, 2);
        const int mask = (ssum != 0.0f) ? 1 : 0;

        const int ids[8] = {n0.x, n0.y, n0.z, n0.w, n1.x, n1.y, n1.z, n1.w};
        unsigned c0 = 0u, c1 = 0u, c2 = 0u;
        #pragma unroll
        for (int kk = 0; kk < 8; ++kk) {
            const unsigned bits = cb_bits[ids[kk]];
            c0 += spread8(bits & 0xFFu);
            c1 += spread8((bits >> 8) & 0xFFu);
            const unsigned t = (bits >> 16) & 3u;
            c2 += (t | (t << 3)) & 0x11u;
        }
        unsigned e0 = c0 & 0x0F0F0F0Fu;
        unsigned e1 = (c0 >> 4) & 0x0F0F0F0Fu;
        unsigned e2 = c1 & 0x0F0F0F0Fu;
        unsigned e3 = (c1 >> 4) & 0x0F0F0F0Fu;
        unsigned e4 = (c2 & 15u) | (((c2 >> 4) & 15u) << 8);
        e0 += __shfl_xor((int)e0, 1); e0 += __shfl_xor((int)e0, 2);
        e1 += __shfl_xor((int)e1, 1); e1 += __shfl_xor((int)e1, 2);
        e2 += __shfl_xor((int)e2, 1); e2 += __shfl_xor((int)e2, 2);
        e3 += __shfl_xor((int)e3, 1); e3 += __shfl_xor((int)e3, 2);
        e4 += __shfl_xor((int)e4, 1); e4 += __shfl_xor((int)e4, 2);

        float rsum = 0.0f;
        #pragma unroll
        for (int i = 0; i < 4; ++i) {
            const unsigned regE = ((i & 1) == 0) ? ((p < 2) ? e0 : e2)
                                                 : ((p < 2) ? e1 : e3);
            const int sh = (((p & 1) * 2) + (i >> 1)) * 8;
            const int cn = (int)((regE >> sh) & 0xFFu);
            const float w = wcv[i];
            const float pos = (yvv[i] != 0.0f) ? lsig(w) : LOG_HALF;
            rsum += pos + (float)cn * lsig(-w) + (float)(NK - cn) * LOG_HALF;
        }
        if (p < 2) {
            const int cn = (int)((e4 >> (p * 8)) & 0xFFu);
            const float pos = (yT != 0.0f) ? lsig(wcT) : LOG_HALF;
            rsum += pos + (float)cn * lsig(-wcT) + (float)(NK - cn) * LOG_HALF;
        }
        rsum += __shfl_xor(rsum, 1);
        rsum += __shfl_xor(rsum, 2);

        float vv = (p == 0 && mask) ? rsum : 0.0f;
        int   mm = (p == 0) ? mask : 0;
        #pragma unroll
        for (int off = 32; off > 0; off >>= 1) {
            vv += __shfl_down(vv, off);
            mm += __shfl_down(mm, off);
        }
        if (lane == 0) { wsum[wv] = vv; wcnt[wv] = mm; }
    }
    __syncthreads();                                        // b4: wus + wsum ready

    // ---- coalesced cooperative W_user store ----
    float* og = out_wu + brow * NA;
    for (int g = tid; g < RPB * NA; g += TPB) {
        const int row = g / NA, col = g - row * NA;
        og[g] = wus[row * 20 + col];
    }
    if (tid == 0) {
        const float s = wsum[0] + wsum[1] + wsum[2] + wsum[3];
        const int   c = wcnt[0] + wcnt[1] + wcnt[2] + wcnt[3];
        blk_part[blockIdx.x] = make_float2(s, (float)c);
    }
}

__global__ __launch_bounds__(FTPB)
void finalize_k(const float2* __restrict__ part, int nblk,
                float* __restrict__ out_loss) {
    __shared__ float ss[FTPB / 64], sc[FTPB / 64];
    float s = 0.f, c = 0.f;
    for (int i = threadIdx.x; i < nblk; i += FTPB) {
        const float2 v = part[i];
        s += v.x; c += v.y;
    }
    #pragma unroll
    for (int off = 32; off > 0; off >>= 1) {
        s += __shfl_down(s, off);
        c += __shfl_down(c, off);
    }
    const int wv = threadIdx.x >> 6;
    if ((threadIdx.x & 63) == 0) { ss[wv] = s; sc[wv] = c; }
    __syncthreads();
    if (threadIdx.x == 0) {
        float S = 0.f, C = 0.f;
        #pragma unroll
        for (int w = 0; w < FTPB / 64; ++w) { S += ss[w]; C += sc[w]; }
        out_loss[0] = -S / fmaxf(C, 1.0f);
    }
}

extern "C" void kernel_launch(void* const* d_in, const int* in_sizes, int n_in,
                              void* d_out, int out_size, void* d_ws, size_t ws_size,
                              hipStream_t stream)
{
    const float* x   = (const float*)d_in[0];
    const float* y   = (const float*)d_in[1];
    const float* ob  = (const float*)d_in[2];
    const float* cb  = (const float*)d_in[3];
    const float* W1  = (const float*)d_in[4];
    const float* b1  = (const float*)d_in[5];
    const float* W2  = (const float*)d_in[6];
    const float* b2  = (const float*)d_in[7];
    const float* W3  = (const float*)d_in[8];
    const float* b3  = (const float*)d_in[9];
    const int*   neg = (const int*)d_in[10];

    const int B = in_sizes[0] / DIM;        // 131072
    const int nblk = B / RPB;               // 2048

    float*    out_wu = (float*)d_out;
    u16*      w1t  = (u16*)d_ws;                          // 40960 B
    u16*      w2t  = (u16*)((char*)d_ws + 40960);         // 4096 B
    u16*      w3t  = (u16*)((char*)d_ws + 45056);         // 2048 B
    unsigned* cbw  = (unsigned*)((char*)d_ws + 47104);    // 1536 B
    float2*   part = (float2*)((char*)d_ws + 48640);      // 16 KiB

    prep_k<<<67, 384, 0, stream>>>(W1, W2, W3, cb, w1t, w2t, w3t, cbw);
    fused_mf2<<<nblk, TPB, 0, stream>>>(x, y, ob, b1, b2, b3,
                                        neg, w1t, w2t, w3t, cbw, out_wu, part);
    finalize_k<<<1, FTPB, 0, stream>>>(part, nblk, out_wu + (long)B * NA);
}

// Round 14
// 51.833 us; speedup vs baseline: 1.1334x; 1.1334x over previous
//
#include <hip/hip_runtime.h>

typedef short bf16x8 __attribute__((ext_vector_type(8)));
typedef unsigned short u16;
typedef u16 u16x4 __attribute__((ext_vector_type(4)));
typedef float f32x4 __attribute__((ext_vector_type(4)));

constexpr int TPB  = 256;
constexpr int RPB  = 64;    // rows per block
constexpr int DIM  = 300;   // embedding dim
constexpr int KPAD = 320;   // padded K (10 x 32)
constexpr int NKT  = 10;    // K-steps of 32
constexpr int H1N  = 64;
constexpr int H2N  = 32;
constexpr int NA   = 18;
constexpr int NK   = 32;
constexpr int NC   = 384;
constexpr float LOG_HALF = -0.6931471805599453f;

__device__ __forceinline__ float fast_sigmoid(float z) {
    return __builtin_amdgcn_rcpf(1.0f + __expf(-z));
}
__device__ __forceinline__ float lsig(float z) {           // stable log(sigmoid(z))
    return fminf(z, 0.0f) - __logf(1.0f + __expf(-fabsf(z)));
}
__device__ __forceinline__ u16 f2bf(float f) {             // f32 -> bf16 RNE
    unsigned u = __builtin_bit_cast(unsigned, f);
    return (u16)((u + 0x7FFFu + ((u >> 16) & 1u)) >> 16);
}
// spread 8 bits to 8 nibbles (bit a -> bit 4a)
__device__ __forceinline__ unsigned spread8(unsigned v) {
    v = (v | (v << 12)) & 0x000F000Fu;
    v = (v | (v << 6))  & 0x03030303u;
    v = (v | (v << 3))  & 0x11111111u;
    return v;
}

// prep: W1->bf16 W1T[64][320], W2->bf16 W2T[32][64], W3->bf16 W3T[32][32] (cols>=18 zero),
//       codebook -> 18-bit masks
__global__ __launch_bounds__(384)
void prep_k(const float* __restrict__ W1, const float* __restrict__ W2,
            const float* __restrict__ W3, const float* __restrict__ cbf,
            u16* __restrict__ w1t, u16* __restrict__ w2t, u16* __restrict__ w3t,
            unsigned* __restrict__ cbw)
{
    const int c = blockIdx.x;
    const int t = threadIdx.x;
    if (c < 64) {
        if (t < KPAD)
            w1t[c * KPAD + t] = f2bf((t < DIM) ? W1[t * H1N + c] : 0.0f);
    } else if (c == 64) {
        if (t < NC) {
            unsigned bits = 0u;
            #pragma unroll
            for (int a = 0; a < NA; ++a)
                bits |= (cbf[t * NA + a] != 0.0f) ? (1u << a) : 0u;
            cbw[t] = bits;
        }
    } else if (c == 65) {
        for (int e = t; e < H2N * H1N; e += 384) {       // w2t[n][k] = W2[k][n]
            const int n = e >> 6, k = e & 63;
            w2t[e] = f2bf(W2[k * H2N + n]);
        }
    } else {
        for (int e = t; e < H2N * H2N; e += 384) {       // w3t[n][k] = W3[k][n], n>=18 -> 0
            const int n = e >> 5, k = e & 31;
            w3t[e] = f2bf((n < NA) ? W3[k * NA + n] : 0.0f);
        }
    }
}

__global__ __launch_bounds__(TPB, 4)
void fused_mf2(const float* __restrict__ x, const float* __restrict__ y,
               const float* __restrict__ ob, const float* __restrict__ b1,
               const float* __restrict__ b2, const float* __restrict__ b3,
               const int* __restrict__ neg_idx,
               const u16* __restrict__ w1t, const u16* __restrict__ w2t,
               const u16* __restrict__ w3t, const unsigned* __restrict__ cbw,
               float* __restrict__ out_wu, float2* __restrict__ blk_part)
{
    __shared__ __align__(16) unsigned char smem[40960];
    u16*      xs      = (u16*)smem;                 // [64][320] bf16, phase 1 only
    u16*      h1s     = (u16*)smem;                 // [64][64]  bf16, bytes 0..8191
    u16*      h2s     = (u16*)(smem + 8192);        // [64][32]  bf16, 4 KiB
    float*    wus     = (float*)(smem + 12288);     // [64][20]  f32,  5120 B
    unsigned* cb_bits = (unsigned*)(smem + 17408);  // 1536 B
    float*    wsum    = (float*)(smem + 18944);
    int*      wcnt    = (int*)(smem + 18960);

    const int tid  = threadIdx.x;
    const int lane = tid & 63;
    const int wv   = tid >> 6;
    const int l15  = lane & 15;
    const int kg   = (lane >> 4) * 8;          // k-group within a K=32 step
    const long brow = (long)blockIdx.x * RPB;
    const float* xg = x + brow * DIM;

    // ---- stage x: pipelined sub-batches, <=13 float4 live (no scratch spill) ----
    // order pinned: LA(7), LB(6), WA, LC(6), WB, WC
    float4 va[7], vb[6], vc[6];
    #pragma unroll
    for (int ch = 0; ch < 7; ++ch)
        va[ch] = *(const float4*)(xg + (long)(ch * TPB + tid) * 4);
    #pragma unroll
    for (int ch = 0; ch < 6; ++ch)
        vb[ch] = *(const float4*)(xg + (long)((7 + ch) * TPB + tid) * 4);
    __builtin_amdgcn_sched_barrier(0);
    #pragma unroll
    for (int ch = 0; ch < 7; ++ch) {                        // WA (waits vmcnt for va only)
        const int f = ch * TPB + tid;
        const int row = f / 75, k = (f - row * 75) * 4;
        const int kk = k ^ ((row & 7) << 3);                // in-row XOR swizzle
        u16x4 pk = { f2bf(va[ch].x), f2bf(va[ch].y), f2bf(va[ch].z), f2bf(va[ch].w) };
        *(u16x4*)(xs + row * KPAD + kk) = pk;
    }
    __builtin_amdgcn_sched_barrier(0);
    #pragma unroll
    for (int ch = 0; ch < 6; ++ch) {                        // LC (last chunk partial)
        const int f = (13 + ch) * TPB + tid;
        vc[ch] = (ch < 5 || f < 4800) ? *(const float4*)(xg + (long)f * 4)
                                      : make_float4(0.f, 0.f, 0.f, 0.f);
    }
    __builtin_amdgcn_sched_barrier(0);
    #pragma unroll
    for (int ch = 0; ch < 6; ++ch) {                        // WB
        const int f = (7 + ch) * TPB + tid;
        const int row = f / 75, k = (f - row * 75) * 4;
        const int kk = k ^ ((row & 7) << 3);
        u16x4 pk = { f2bf(vb[ch].x), f2bf(vb[ch].y), f2bf(vb[ch].z), f2bf(vb[ch].w) };
        *(u16x4*)(xs + row * KPAD + kk) = pk;
    }
    #pragma unroll
    for (int ch = 0; ch < 6; ++ch) {                        // WC
        const int f = (13 + ch) * TPB + tid;
        if (ch < 5 || f < 4800) {
            const int row = f / 75, k = (f - row * 75) * 4;
            const int kk = k ^ ((row & 7) << 3);
            u16x4 pk = { f2bf(vc[ch].x), f2bf(vc[ch].y), f2bf(vc[ch].z), f2bf(vc[ch].w) };
            *(u16x4*)(xs + row * KPAD + kk) = pk;
        }
    }
    #pragma unroll
    for (int uu = 0; uu < 5; ++uu) {                        // zero-pad k in [300,320)
        const int e = uu * TPB + tid;
        const int row = e / 20, kp = e - row * 20;
        xs[row * KPAD + ((DIM + kp) ^ ((row & 7) << 3))] = 0;
    }

    // ---- W1 B-frags (L2-hot) + codebook regs; b1 drains vmcnt anyway ----
    const int colB = wv * 16 + l15;
    bf16x8 bfr[NKT];                                        // 40 VGPR
    #pragma unroll
    for (int kt = 0; kt < NKT; ++kt)
        bfr[kt] = *(const bf16x8*)(w1t + colB * KPAD + kt * 32 + kg);
    const unsigned cbv0 = cbw[tid];
    const unsigned cbv1 = (tid < NC - TPB) ? cbw[tid + TPB] : 0u;

    __syncthreads();                                        // b1: xs ready

    // ---- phase 1: x @ W1 (4 row-tiles x 10 K-steps) ----
    f32x4 acc[4];
    #pragma unroll
    for (int rt = 0; rt < 4; ++rt) acc[rt] = (f32x4){0.f, 0.f, 0.f, 0.f};
    #pragma unroll
    for (int kt = 0; kt < NKT; ++kt) {
        bf16x8 afr[4];
        #pragma unroll
        for (int rt = 0; rt < 4; ++rt) {
            const int row = rt * 16 + l15;
            afr[rt] = *(const bf16x8*)(xs + ((row * KPAD + kt * 32 + kg) ^ ((row & 7) << 3)));
        }
        #pragma unroll
        for (int rt = 0; rt < 4; ++rt)
            acc[rt] = __builtin_amdgcn_mfma_f32_16x16x32_bf16(afr[rt], bfr[kt], acc[rt], 0, 0, 0);
    }
    __syncthreads();                                        // b2: xs reads done

    // ---- epilogue 1: bias+sigmoid -> h1s (swizzled, aliases xs) ----
    const float b1v = b1[colB];
    #pragma unroll
    for (int rt = 0; rt < 4; ++rt) {
        #pragma unroll
        for (int j = 0; j < 4; ++j) {
            const int row = rt * 16 + (lane >> 4) * 4 + j;  // C/D map (m89)
            h1s[(row * H1N + colB) ^ ((row & 7) << 3)] = f2bf(fast_sigmoid(acc[rt][j] + b1v));
        }
    }
    cb_bits[tid] = cbv0;
    if (tid < NC - TPB) cb_bits[tid + TPB] = cbv1;

    // ---- loss-input loads: issued here (low reg pressure), fly under phases 2-3 ----
    const int rloc = wv * 16 + (lane >> 2);
    const int p    = lane & 3;
    const long bds = brow + rloc;
    const int4* nbp = (const int4*)(neg_idx + bds * NK + p * 8);
    const int4 n0 = nbp[0], n1 = nbp[1];
    const float* obr = ob + bds * NA + p * 4;
    const float2 oA = *(const float2*)obr, oB = *(const float2*)(obr + 2);
    const float  oT = (p < 2) ? ob[bds * NA + 16 + p] : 0.f;
    const float* yr = y + bds * NA + p * 4;
    const float2 yA = *(const float2*)yr, yB = *(const float2*)(yr + 2);
    const float  yT = (p < 2) ? y[bds * NA + 16 + p] : 0.f;

    __syncthreads();                                        // b3: h1s + cb ready

    // ---- phase 2: h1 @ W2 via MFMA (wave owns rows 16wv..16wv+15) ----
    const int rowA = wv * 16 + l15;
    bf16x8 a2[2];
    #pragma unroll
    for (int kt = 0; kt < 2; ++kt)
        a2[kt] = *(const bf16x8*)(h1s + ((rowA * H1N + kt * 32 + kg) ^ ((rowA & 7) << 3)));
    f32x4 acc2[2];
    #pragma unroll
    for (int ct = 0; ct < 2; ++ct) {
        const float bb = b2[ct * 16 + l15];
        acc2[ct] = (f32x4){bb, bb, bb, bb};
    }
    #pragma unroll
    for (int ct = 0; ct < 2; ++ct)
        #pragma unroll
        for (int kt = 0; kt < 2; ++kt) {
            const bf16x8 bfr2 = *(const bf16x8*)(w2t + (ct * 16 + l15) * H1N + kt * 32 + kg);
            acc2[ct] = __builtin_amdgcn_mfma_f32_16x16x32_bf16(a2[kt], bfr2, acc2[ct], 0, 0, 0);
        }
    #pragma unroll
    for (int ct = 0; ct < 2; ++ct) {
        #pragma unroll
        for (int j = 0; j < 4; ++j) {
            const int row = wv * 16 + (lane >> 4) * 4 + j;
            const int col = ct * 16 + l15;
            h2s[(row * H2N + col) ^ ((row & 3) << 3)] = f2bf(fast_sigmoid(acc2[ct][j]));
        }
    }

    // ---- phase 3: h2 @ W3 (same-wave rows; lgkmcnt orders write->read) ----
    const bf16x8 a3 = *(const bf16x8*)(h2s + ((rowA * H2N + kg) ^ ((rowA & 3) << 3)));
    f32x4 acc3[2];
    #pragma unroll
    for (int ct = 0; ct < 2; ++ct) {
        const int col = ct * 16 + l15;
        const float bb = (col < NA) ? b3[col] : 0.f;
        acc3[ct] = (f32x4){bb, bb, bb, bb};
    }
    #pragma unroll
    for (int ct = 0; ct < 2; ++ct) {
        const bf16x8 bfr3 = *(const bf16x8*)(w3t + (ct * 16 + l15) * H2N + kg);
        acc3[ct] = __builtin_amdgcn_mfma_f32_16x16x32_bf16(a3, bfr3, acc3[ct], 0, 0, 0);
    }
    // wu -> wus LDS [64][20] f32 (own-wave rows)
    #pragma unroll
    for (int j = 0; j < 4; ++j) {
        const int row = wv * 16 + (lane >> 4) * 4 + j;
        wus[row * 20 + l15] = acc3[0][j];
        if (l15 < 2) wus[row * 20 + 16 + l15] = acc3[1][j];
    }
    __builtin_amdgcn_sched_barrier(0);                      // keep reads after writes

    // ---- loss: 4 lanes/row, reading own-wave wus rows ----
    const float4 wA = *(const float4*)(wus + rloc * 20 + p * 4);
    const float  wT = (p < 2) ? wus[rloc * 20 + 16 + p] : 0.f;

    const float wcv[4] = {wA.x * oA.x, wA.y * oA.y, wA.z * oB.x, wA.w * oB.y};
    const float yvv[4] = {yA.x, yA.y, yB.x, yB.y};
    const float wcT = wT * oT;
    float ssum = wcv[0] + wcv[1] + wcv[2] + wcv[3] + wcT;
    ssum += __shfl_xor(ssum, 1);
    ssum += __shfl_xor(ssum, 2);
    const int mask = (ssum != 0.0f) ? 1 : 0;

    const int ids[8] = {n0.x, n0.y, n0.z, n0.w, n1.x, n1.y, n1.z, n1.w};
    unsigned c0 = 0u, c1 = 0u, c2 = 0u;
    #pragma unroll
    for (int kk = 0; kk < 8; ++kk) {
        const unsigned bits = cb_bits[ids[kk]];
        c0 += spread8(bits & 0xFFu);
        c1 += spread8((bits >> 8) & 0xFFu);
        const unsigned t = (bits >> 16) & 3u;
        c2 += (t | (t << 3)) & 0x11u;
    }
    unsigned e0 = c0 & 0x0F0F0F0Fu;
    unsigned e1 = (c0 >> 4) & 0x0F0F0F0Fu;
    unsigned e2 = c1 & 0x0F0F0F0Fu;
    unsigned e3 = (c1 >> 4) & 0x0F0F0F0Fu;
    unsigned e4 = (c2 & 15u) | (((c2 >> 4) & 15u) << 8);
    e0 += __shfl_xor((int)e0, 1); e0 += __shfl_xor((int)e0, 2);
    e1 += __shfl_xor((int)e1, 1); e1 += __shfl_xor((int)e1, 2);
    e2 += __shfl_xor((int)e2, 1); e2 += __shfl_xor((int)e2, 2);
    e3 += __shfl_xor((int)e3, 1); e3 += __shfl_xor((int)e3, 2);
    e4 += __shfl_xor((int)e4, 1); e4 += __shfl_xor((int)e4, 2);

    float rsum = 0.0f;
    #pragma unroll
    for (int i = 0; i < 4; ++i) {
        const unsigned regE = ((i & 1) == 0) ? ((p < 2) ? e0 : e2)
                                             : ((p < 2) ? e1 : e3);
        const int sh = (((p & 1) * 2) + (i >> 1)) * 8;
        const int cn = (int)((regE >> sh) & 0xFFu);
        const float w = wcv[i];
        const float pos = (yvv[i] != 0.0f) ? lsig(w) : LOG_HALF;
        rsum += pos + (float)cn * lsig(-w) + (float)(NK - cn) * LOG_HALF;
    }
    if (p < 2) {
        const int cn = (int)((e4 >> (p * 8)) & 0xFFu);
        const float pos = (yT != 0.0f) ? lsig(wcT) : LOG_HALF;
        rsum += pos + (float)cn * lsig(-wcT) + (float)(NK - cn) * LOG_HALF;
    }
    rsum += __shfl_xor(rsum, 1);
    rsum += __shfl_xor(rsum, 2);

    float vv = (p == 0 && mask) ? rsum : 0.0f;
    int   mm = (p == 0) ? mask : 0;
    #pragma unroll
    for (int off = 32; off > 0; off >>= 1) {
        vv += __shfl_down(vv, off);
        mm += __shfl_down(mm, off);
    }
    if (lane == 0) { wsum[wv] = vv; wcnt[wv] = mm; }
    __syncthreads();                                        // b4: wus + wsum ready

    // ---- coalesced cooperative W_user store ----
    float* og = out_wu + brow * NA;
    #pragma unroll
    for (int g = tid; g < RPB * NA; g += TPB) {
        const int row = g / NA, col = g - row * NA;
        og[g] = wus[row * 20 + col];
    }
    if (tid == 0) {
        const float s = wsum[0] + wsum[1] + wsum[2] + wsum[3];
        const int   c = wcnt[0] + wcnt[1] + wcnt[2] + wcnt[3];
        blk_part[blockIdx.x] = make_float2(s, (float)c);
    }
}

__global__ void finalize_k(const float2* __restrict__ part, int nblk,
                           float* __restrict__ out_loss) {
    __shared__ float ss[4], sc[4];
    float s = 0.f, c = 0.f;
    for (int i = threadIdx.x; i < nblk; i += 256) {
        const float2 v = part[i];
        s += v.x; c += v.y;
    }
    #pragma unroll
    for (int off = 32; off > 0; off >>= 1) {
        s += __shfl_down(s, off);
        c += __shfl_down(c, off);
    }
    const int wv = threadIdx.x >> 6;
    if ((threadIdx.x & 63) == 0) { ss[wv] = s; sc[wv] = c; }
    __syncthreads();
    if (threadIdx.x == 0) {
        const float S = ss[0] + ss[1] + ss[2] + ss[3];
        const float C = sc[0] + sc[1] + sc[2] + sc[3];
        out_loss[0] = -S / fmaxf(C, 1.0f);
    }
}

extern "C" void kernel_launch(void* const* d_in, const int* in_sizes, int n_in,
                              void* d_out, int out_size, void* d_ws, size_t ws_size,
                              hipStream_t stream)
{
    const float* x   = (const float*)d_in[0];
    const float* y   = (const float*)d_in[1];
    const float* ob  = (const float*)d_in[2];
    const float* cb  = (const float*)d_in[3];
    const float* W1  = (const float*)d_in[4];
    const float* b1  = (const float*)d_in[5];
    const float* W2  = (const float*)d_in[6];
    const float* b2  = (const float*)d_in[7];
    const float* W3  = (const float*)d_in[8];
    const float* b3  = (const float*)d_in[9];
    const int*   neg = (const int*)d_in[10];

    const int B = in_sizes[0] / DIM;        // 131072
    const int nblk = B / RPB;               // 2048

    float*    out_wu = (float*)d_out;
    u16*      w1t  = (u16*)d_ws;                          // 40960 B
    u16*      w2t  = (u16*)((char*)d_ws + 40960);         // 4096 B
    u16*      w3t  = (u16*)((char*)d_ws + 45056);         // 2048 B
    unsigned* cbw  = (unsigned*)((char*)d_ws + 47104);    // 1536 B
    float2*   part = (float2*)((char*)d_ws + 48640);      // 16 KiB

    prep_k<<<67, 384, 0, stream>>>(W1, W2, W3, cb, w1t, w2t, w3t, cbw);
    fused_mf2<<<nblk, TPB, 0, stream>>>(x, y, ob, b1, b2, b3,
                                        neg, w1t, w2t, w3t, cbw, out_wu, part);
    finalize_k<<<1, 256, 0, stream>>>(part, nblk, out_wu + (long)B * NA);
}